// Round 5
// baseline (483.275 us; speedup 1.0000x reference)
//
#include <hip/hip_runtime.h>
#include <math.h>

#define B_ 2
#define N_ 25000
#define E_ 400000
#define D_ 128
#define NRBF 64

#define TPB 256               // 4 waves
#define NTILES 25             // tiles per wave; 16 edges per wave-tile
#define WCH 400               // edges per wave (16 * 25)
#define GCH 100               // edges per (wave, lane-quad) contiguous chunk
#define EPB (4 * WCH)         // 1600 edges per block
#define NBLK (E_ / EPB)       // 250 blocks per batch

typedef short bf8    __attribute__((ext_vector_type(8)));   // MFMA A/B frag
typedef float f32x4  __attribute__((ext_vector_type(4)));   // MFMA C/D frag
typedef float vf8    __attribute__((ext_vector_type(8)));
typedef unsigned int u32;
typedef u32 u32x4    __attribute__((ext_vector_type(4)));

// pack two f32 -> one u32 holding [bf16(hi) : bf16(lo)], round-half-up (hot path)
__device__ __forceinline__ u32 pack2(float hi, float lo) {
    union { float f; u32 u; } a, b; a.f = hi; b.f = lo;
    return __builtin_amdgcn_perm(a.u + 0x8000u, b.u + 0x8000u, 0x07060302u);
}
// RNE variant for weights (one-time)
__device__ __forceinline__ u32 pack2rne(float hi, float lo) {
    union { float f; u32 u; } a, b; a.f = hi; b.f = lo;
    u32 au = a.u + 0x7FFFu + ((a.u >> 16) & 1u);
    u32 bu = b.u + 0x7FFFu + ((b.u >> 16) & 1u);
    return __builtin_amdgcn_perm(au, bu, 0x07060302u);
}
__device__ __forceinline__ short f2bf(float f) {
    union { float f; u32 u; } v; v.f = f;
    return (short)((v.u + 0x7FFFu + ((v.u >> 16) & 1u)) >> 16);
}
// shifted softplus: softplus(x) - ln(2)
__device__ __forceinline__ float ssp(float x) {
    float t = __expf(-fabsf(x));
    float l = __logf(1.0f + t);                       // ln(1+e^-|x|)
    return (fmaxf(x, 0.0f) - 0.69314718056f) + l;
}

__global__ __launch_bounds__(TPB, 2)
void cfconv_kernel(const float* __restrict__ af,      // [B,N,D]
                   const float* __restrict__ dist,    // [B,E]
                   const int*   __restrict__ idx_j,   // [E]
                   const int*   __restrict__ seg_i,   // [E] (sorted)
                   const float* __restrict__ centers, // [NRBF]
                   const float* __restrict__ gam,     // [NRBF]
                   const float* __restrict__ W1,      // [NRBF,D]
                   const float* __restrict__ b1,      // [D]
                   const float* __restrict__ W2,      // [D,D]
                   const float* __restrict__ b2,      // [D]
                   float* __restrict__ out)           // [B,N,D]
{
    const int t    = threadIdx.x;
    const int lane = t & 63;
    const int w    = t >> 6;          // wave 0..3
    const int g    = lane >> 4;       // quad 0..3
    const int c0   = lane & 15;
    const int b    = blockIdx.y;
    const int e0   = blockIdx.x * EPB;

    // W2 fragment-ready: [cc][g][n][j], B[k][n], k = cc*32+g*8+j  (32 KB)
    __shared__ __align__(16) short W2f[4 * 4 * D_ * 8];
    // per-wave h1 in A-frag order: [wave][c0w][m_phys][j]  (16 KB)
    __shared__ __align__(16) short A2[4][16][16][8];

    // ---- stage W2 -> LDS frag layout (one-time, coalesced-ish)
    for (int i = t; i < D_ * D_; i += TPB) {
        const int k = i >> 7, n = i & 127;
        W2f[(((k >> 5) * 4 + ((k >> 3) & 3)) * D_ + n) * 8 + (k & 7)] = f2bf(W2[i]);
    }
    __syncthreads();   // ONLY barrier in the kernel

    // ---- W1 fragments into registers, with permuted column order:
    // GEMM1 col c = nt*16 + c0  carries  k2 = 8*c0 + nt
    // w1r[cc*8+nt][j] = W1[cc*32 + g*8 + j][8*c0 + nt]
    bf8 w1r[16];
    #pragma unroll
    for (int cc = 0; cc < 2; ++cc) {
        vf8 row[8];
        #pragma unroll
        for (int j = 0; j < 8; ++j)
            row[j] = *(const vf8*)&W1[(size_t)(cc * 32 + g * 8 + j) * D_ + 8 * c0];
        #pragma unroll
        for (int nt = 0; nt < 8; ++nt) {
            u32x4 q;
            #pragma unroll
            for (int p = 0; p < 4; ++p)
                q[p] = pack2rne(row[2 * p + 1][nt], row[2 * p][nt]);
            w1r[cc * 8 + nt] = __builtin_bit_cast(bf8, q);
        }
    }

    // biases: GEMM1 col (nt*16+c0) -> b1[8*c0+nt]; GEMM2 col -> b2[nt*16+c0]
    const vf8 b1r = *(const vf8*)&b1[8 * c0];
    vf8 b2r;
    #pragma unroll
    for (int nt = 0; nt < 8; ++nt) b2r[nt] = b2[nt * 16 + c0];

    // rbf params for this lane's A-frag rows: k = cc*32 + g*8 + j
    vf8 gla, glb, cla, clb;
    #pragma unroll
    for (int j = 0; j < 8; ++j) {
        gla[j] = gam[g * 8 + j]      * 1.44269504f;   // pre-mul log2(e)
        glb[j] = gam[32 + g * 8 + j] * 1.44269504f;
        cla[j] = centers[g * 8 + j];
        clb[j] = centers[32 + g * 8 + j];
    }

    const float* dist_b = dist + (size_t)b * E_;
    const float* af_b   = af   + (size_t)b * N_ * D_;
    float*       out_b  = out  + (size_t)b * N_ * D_;

    // edge owned by A-row m=c0 at tile s: e0 + w*WCH + (c0>>2)*GCH + s*4 + (c0&3)
    const int eArow = e0 + w * WCH + (c0 >> 2) * GCH + (c0 & 3);
    // epilogue: quad g owns edges ebase + s*4 + r
    const int ebase = e0 + w * WCH + g * GCH;

    int cur_seg = -1;
    vf8 pend = (vf8)0.0f;

    for (int s = 0; s < NTILES; ++s) {
        // ===== rbf A-fragments, in-register =====
        const float dd = dist_b[eArow + s * 4];
        u32x4 qa, qb;
        #pragma unroll
        for (int p = 0; p < 4; ++p) {
            float x0 = dd - cla[2 * p];     float v0 = exp2f(-gla[2 * p]     * x0 * x0);
            float x1 = dd - cla[2 * p + 1]; float v1 = exp2f(-gla[2 * p + 1] * x1 * x1);
            qa[p] = pack2(v1, v0);
            float y0 = dd - clb[2 * p];     float u0 = exp2f(-glb[2 * p]     * y0 * y0);
            float y1 = dd - clb[2 * p + 1]; float u1 = exp2f(-glb[2 * p + 1] * y1 * y1);
            qb[p] = pack2(u1, u0);
        }
        const bf8 a0 = __builtin_bit_cast(bf8, qa);
        const bf8 a1 = __builtin_bit_cast(bf8, qb);

        // ===== GEMM1: h1 (cols = permuted k2) =====
        f32x4 hh[8];
        #pragma unroll
        for (int nt = 0; nt < 8; ++nt) {
            f32x4 acc = {0.f, 0.f, 0.f, 0.f};
            acc = __builtin_amdgcn_mfma_f32_16x16x32_bf16(a0, w1r[nt],     acc, 0, 0, 0);
            acc = __builtin_amdgcn_mfma_f32_16x16x32_bf16(a1, w1r[8 + nt], acc, 0, 0, 0);
            hh[nt] = acc;
        }

        // ===== ssp + pack + swizzled b128 store to per-wave A2 =====
        // C value (row m'=g*4+r, col nt*16+c0) == h1[edge m'][k2 = 8*c0+nt]
        #pragma unroll
        for (int r = 0; r < 4; ++r) {
            u32x4 q;
            #pragma unroll
            for (int p = 0; p < 4; ++p) {
                float v0 = ssp(hh[2 * p][r]     + b1r[2 * p]);
                float v1 = ssp(hh[2 * p + 1][r] + b1r[2 * p + 1]);
                q[p] = pack2(v1, v0);
            }
            const int mphys = (g * 4 + r) ^ (c0 & 7);
            *(bf8*)&A2[w][c0][mphys][0] = __builtin_bit_cast(bf8, q);
        }
        // intra-wave only: compiler inserts lgkmcnt before dependent reads

        // ===== GEMM2 A-frags from own wave's A2 =====
        f32x4 facc[8];
        {
            bf8 pfr[4];
            #pragma unroll
            for (int cc = 0; cc < 4; ++cc) {
                const int c0w = cc * 4 + g;
                pfr[cc] = *(const bf8*)&A2[w][c0w][c0 ^ (c0w & 7)][0];
            }
            #pragma unroll
            for (int nt = 0; nt < 8; ++nt) {
                f32x4 acc = {0.f, 0.f, 0.f, 0.f};
                #pragma unroll
                for (int cc = 0; cc < 4; ++cc) {
                    const bf8 wf = *(const bf8*)&W2f[((cc * 4 + g) * D_ + nt * 16 + c0) * 8];
                    acc = __builtin_amdgcn_mfma_f32_16x16x32_bf16(pfr[cc], wf, acc, 0, 0, 0);
                }
                facc[nt] = acc;
            }
        }

        // ===== epilogue: ssp, gather*filter, sorted-run combine, atomics =====
        #pragma unroll
        for (int r = 0; r < 4; ++r) {
            const int e  = ebase + s * 4 + r;
            const int j  = idx_j[e];       // uniform within quad -> broadcast
            const int sg = seg_i[e];
            const float* row = af_b + (size_t)j * D_ + c0;
            vf8 msg;
            #pragma unroll
            for (int nt = 0; nt < 8; ++nt) {
                const float fv = ssp(facc[nt][r] + b2r[nt]);
                msg[nt] = row[nt * 16] * fv;
            }
            if (sg != cur_seg) {
                if (cur_seg >= 0) {
                    float* o = out_b + (size_t)cur_seg * D_ + c0;
                    #pragma unroll
                    for (int nt = 0; nt < 8; ++nt) atomicAdd(o + nt * 16, pend[nt]);
                }
                cur_seg = sg;
                pend = msg;
            } else {
                pend += msg;
            }
        }
    }
    if (cur_seg >= 0) {
        float* o = out_b + (size_t)cur_seg * D_ + c0;
        #pragma unroll
        for (int nt = 0; nt < 8; ++nt) atomicAdd(o + nt * 16, pend[nt]);
    }
}

extern "C" void kernel_launch(void* const* d_in, const int* in_sizes, int n_in,
                              void* d_out, int out_size, void* d_ws, size_t ws_size,
                              hipStream_t stream) {
    const float* af      = (const float*)d_in[0];
    const float* dist    = (const float*)d_in[1];
    const int*   idx_j   = (const int*)d_in[2];
    const int*   seg_i   = (const int*)d_in[3];
    const float* centers = (const float*)d_in[4];
    const float* gam     = (const float*)d_in[5];
    const float* W1      = (const float*)d_in[6];
    const float* b1      = (const float*)d_in[7];
    const float* W2      = (const float*)d_in[8];
    const float* b2      = (const float*)d_in[9];
    float* out = (float*)d_out;

    hipMemsetAsync(out, 0, (size_t)out_size * sizeof(float), stream);

    dim3 grid(NBLK, B_);
    cfconv_kernel<<<grid, TPB, 0, stream>>>(af, dist, idx_j, seg_i,
                                            centers, gam, W1, b1, W2, b2, out);
}

// Round 6
// 470.365 us; speedup vs baseline: 1.0274x; 1.0274x over previous
//
#include <hip/hip_runtime.h>
#include <math.h>

#define B_ 2
#define N_ 25000
#define E_ 400000
#define D_ 128
#define NRBF 64

#define TPB 256               // 4 waves
#define NTILES 25             // tiles per wave; 16 edges per wave-tile
#define WCH 400               // edges per wave
#define GCH 100               // edges per (wave, lane-quad) contiguous chunk
#define EPB (4 * WCH)         // 1600 edges per block
#define NBLK (E_ / EPB)       // 250 blocks per batch

typedef short bf8    __attribute__((ext_vector_type(8)));   // MFMA A/B frag
typedef float f32x4  __attribute__((ext_vector_type(4)));   // MFMA C/D frag
typedef float vf8    __attribute__((ext_vector_type(8)));
typedef unsigned int u32;
typedef u32 u32x4    __attribute__((ext_vector_type(4)));

// pack two f32 -> u32 [bf16(hi):bf16(lo)], round-half-up (hot path)
__device__ __forceinline__ u32 pack2(float hi, float lo) {
    union { float f; u32 u; } a, b; a.f = hi; b.f = lo;
    return __builtin_amdgcn_perm(a.u + 0x8000u, b.u + 0x8000u, 0x07060302u);
}
__device__ __forceinline__ short f2bf(float f) {   // RNE, one-time paths
    union { float f; u32 u; } v; v.f = f;
    return (short)((v.u + 0x7FFFu + ((v.u >> 16) & 1u)) >> 16);
}
// shifted softplus: softplus(x) - ln(2)
__device__ __forceinline__ float ssp(float x) {
    float t = __expf(-fabsf(x));
    float l = __logf(1.0f + t);
    return (fmaxf(x, 0.0f) - 0.69314718056f) + l;
}

__global__ __launch_bounds__(TPB, 2)
void cfconv_kernel(const float* __restrict__ af,      // [B,N,D]
                   const float* __restrict__ dist,    // [B,E]
                   const int*   __restrict__ idx_j,   // [E]
                   const int*   __restrict__ seg_i,   // [E] (sorted)
                   const float* __restrict__ centers, // [NRBF]
                   const float* __restrict__ gam,     // [NRBF]
                   const float* __restrict__ W1,      // [NRBF,D]
                   const float* __restrict__ b1,      // [D]
                   const float* __restrict__ W2,      // [D,D]
                   const float* __restrict__ b2,      // [D]
                   float* __restrict__ out)           // [B,N,D]
{
    const int t    = threadIdx.x;
    const int lane = t & 63;
    const int w    = t >> 6;          // wave 0..3
    const int g    = lane >> 4;       // quad 0..3
    const int c0   = lane & 15;
    const int b    = blockIdx.y;
    const int e0   = blockIdx.x * EPB;

    // fragment-ready bf16 weights, PERMUTED columns:
    //   physical col c carries logical col 8*(c&15) + (c>>4)
    //   layout [cc][g][c][j], B[k][.], k = cc*32 + g*8 + j
    __shared__ __align__(16) short W1f[2 * 4 * D_ * 8];     // 16 KB
    __shared__ __align__(16) short W2f[4 * 4 * D_ * 8];     // 32 KB
    // per-wave h1, A-frag order: A2[w][c0w][m_swz][j] = h1[m][8*c0w+j]  (16 KB)
    __shared__ __align__(16) short A2[4][16][16][8];

    // ---- one-time: weights -> LDS frag layout (permuted logical columns)
    for (int i = t; i < NRBF * D_; i += TPB) {
        const int k = i >> 7, c = i & 127;
        W1f[(((k >> 5) * 4 + ((k >> 3) & 3)) * D_ + c) * 8 + (k & 7)] =
            f2bf(W1[(size_t)k * D_ + 8 * (c & 15) + (c >> 4)]);
    }
    for (int i = t; i < D_ * D_; i += TPB) {
        const int k = i >> 7, c = i & 127;
        W2f[(((k >> 5) * 4 + ((k >> 3) & 3)) * D_ + c) * 8 + (k & 7)] =
            f2bf(W2[(size_t)k * D_ + 8 * (c & 15) + (c >> 4)]);
    }
    __syncthreads();   // only block-wide barrier

    // biases in logical (permuted) order: col nt -> b[8*c0+nt]
    const vf8 b1r = *(const vf8*)&b1[8 * c0];
    const vf8 b2r = *(const vf8*)&b2[8 * c0];

    // rbf params for this lane's A-frag rows: k = cc*32 + g*8 + j
    vf8 gla, glb, cla, clb;
    #pragma unroll
    for (int j = 0; j < 8; ++j) {
        gla[j] = gam[g * 8 + j]      * 1.44269504f;   // pre-mul log2(e)
        glb[j] = gam[32 + g * 8 + j] * 1.44269504f;
        cla[j] = centers[g * 8 + j];
        clb[j] = centers[32 + g * 8 + j];
    }

    const float* dist_b = dist + (size_t)b * E_;
    const float* af_b   = af   + (size_t)b * N_ * D_;
    float*       out_b  = out  + (size_t)b * N_ * D_;

    const int eArow = e0 + w * WCH + (c0 >> 2) * GCH + (c0 & 3);  // A-row m=c0
    const int ebase = e0 + w * WCH + g * GCH;                     // epilogue quad

    int cur_seg = -1;
    vf8 pend = (vf8)0.0f;

    for (int s = 0; s < NTILES; ++s) {
        // ===== rbf A-fragments in registers =====
        const float dd = dist_b[eArow + s * 4];
        u32x4 qa, qb;
        #pragma unroll
        for (int p = 0; p < 4; ++p) {
            float x0 = dd - cla[2 * p];     float v0 = __builtin_amdgcn_exp2f(-gla[2 * p]     * x0 * x0);
            float x1 = dd - cla[2 * p + 1]; float v1 = __builtin_amdgcn_exp2f(-gla[2 * p + 1] * x1 * x1);
            qa[p] = pack2(v1, v0);
            float y0 = dd - clb[2 * p];     float u0 = __builtin_amdgcn_exp2f(-glb[2 * p]     * y0 * y0);
            float y1 = dd - clb[2 * p + 1]; float u1 = __builtin_amdgcn_exp2f(-glb[2 * p + 1] * y1 * y1);
            qb[p] = pack2(u1, u0);
        }
        const bf8 a0 = __builtin_bit_cast(bf8, qa);
        const bf8 a1 = __builtin_bit_cast(bf8, qb);

        // ===== GEMM1: h1 (cols permuted: phys nt*16+c0 -> logical 8*c0+nt) =====
        f32x4 hh[8];
        #pragma unroll
        for (int nt = 0; nt < 8; ++nt) {
            const bf8 w0 = *(const bf8*)&W1f[((0 * 4 + g) * D_ + nt * 16 + c0) * 8];
            const bf8 w1 = *(const bf8*)&W1f[((1 * 4 + g) * D_ + nt * 16 + c0) * 8];
            f32x4 acc = {0.f, 0.f, 0.f, 0.f};
            acc = __builtin_amdgcn_mfma_f32_16x16x32_bf16(a0, w0, acc, 0, 0, 0);
            acc = __builtin_amdgcn_mfma_f32_16x16x32_bf16(a1, w1, acc, 0, 0, 0);
            hh[nt] = acc;
        }

        // ===== ssp + pack + swizzled b128 store to per-wave A2 =====
        #pragma unroll
        for (int r = 0; r < 4; ++r) {
            u32x4 q;
            #pragma unroll
            for (int p = 0; p < 4; ++p) {
                float v0 = ssp(hh[2 * p][r]     + b1r[2 * p]);
                float v1 = ssp(hh[2 * p + 1][r] + b1r[2 * p + 1]);
                q[p] = pack2(v1, v0);
            }
            const int mphys = (g * 4 + r) ^ (c0 & 7);
            *(bf8*)&A2[w][c0][mphys][0] = __builtin_bit_cast(bf8, q);
        }
        // intra-wave dependency only (compiler inserts lgkmcnt)

        // ===== GEMM2 =====
        f32x4 facc[8];
        {
            bf8 pfr[4];
            #pragma unroll
            for (int cc = 0; cc < 4; ++cc) {
                const int c0w = cc * 4 + g;
                pfr[cc] = *(const bf8*)&A2[w][c0w][c0 ^ (c0w & 7)][0];
            }
            #pragma unroll
            for (int nt = 0; nt < 8; ++nt) {
                f32x4 acc = {0.f, 0.f, 0.f, 0.f};
                #pragma unroll
                for (int cc = 0; cc < 4; ++cc) {
                    const bf8 wf = *(const bf8*)&W2f[((cc * 4 + g) * D_ + nt * 16 + c0) * 8];
                    acc = __builtin_amdgcn_mfma_f32_16x16x32_bf16(pfr[cc], wf, acc, 0, 0, 0);
                }
                facc[nt] = acc;
            }
        }

        // ===== epilogue: contiguous gather, ssp, run-combine, atomics =====
        #pragma unroll
        for (int r = 0; r < 4; ++r) {
            const int e  = ebase + s * 4 + r;
            const int j  = idx_j[e];
            const int sg = seg_i[e];
            const vf8 nb = *(const vf8*)&af_b[(size_t)j * D_ + 8 * c0];  // 2x dwordx4
            vf8 msg;
            #pragma unroll
            for (int nt = 0; nt < 8; ++nt) {
                const float fv = ssp(facc[nt][r] + b2r[nt]);   // logical col 8*c0+nt
                msg[nt] = nb[nt] * fv;
            }
            if (sg != cur_seg) {
                if (cur_seg >= 0) {
                    float* o = out_b + (size_t)cur_seg * D_ + 8 * c0;
                    #pragma unroll
                    for (int nt = 0; nt < 8; ++nt) atomicAdd(o + nt, pend[nt]);
                }
                cur_seg = sg;
                pend = msg;
            } else {
                pend += msg;
            }
        }
    }
    if (cur_seg >= 0) {
        float* o = out_b + (size_t)cur_seg * D_ + 8 * c0;
        #pragma unroll
        for (int nt = 0; nt < 8; ++nt) atomicAdd(o + nt, pend[nt]);
    }
}

extern "C" void kernel_launch(void* const* d_in, const int* in_sizes, int n_in,
                              void* d_out, int out_size, void* d_ws, size_t ws_size,
                              hipStream_t stream) {
    const float* af      = (const float*)d_in[0];
    const float* dist    = (const float*)d_in[1];
    const int*   idx_j   = (const int*)d_in[2];
    const int*   seg_i   = (const int*)d_in[3];
    const float* centers = (const float*)d_in[4];
    const float* gam     = (const float*)d_in[5];
    const float* W1      = (const float*)d_in[6];
    const float* b1      = (const float*)d_in[7];
    const float* W2      = (const float*)d_in[8];
    const float* b2      = (const float*)d_in[9];
    float* out = (float*)d_out;

    hipMemsetAsync(out, 0, (size_t)out_size * sizeof(float), stream);

    dim3 grid(NBLK, B_);
    cfconv_kernel<<<grid, TPB, 0, stream>>>(af, dist, idx_j, seg_i,
                                            centers, gam, W1, b1, W2, b2, out);
}

// Round 7
// 469.376 us; speedup vs baseline: 1.0296x; 1.0021x over previous
//
#include <hip/hip_runtime.h>
#include <math.h>

#define B_ 2
#define N_ 25000
#define E_ 400000
#define D_ 128
#define NRBF 64

#define TPB 256               // 4 waves
#define NTILES 25             // tiles per wave; 16 edges per wave-tile
#define WCH 400               // edges per wave
#define GCH 100               // edges per (wave, lane-quad) contiguous chunk
#define EPB (4 * WCH)         // 1600 edges per block
#define NBLK (E_ / EPB)       // 250 blocks per batch

typedef short bf8    __attribute__((ext_vector_type(8)));   // MFMA A/B frag
typedef float f32x4  __attribute__((ext_vector_type(4)));   // MFMA C/D frag
typedef float vf8    __attribute__((ext_vector_type(8)));
typedef unsigned int u32;
typedef u32 u32x4    __attribute__((ext_vector_type(4)));

// pack two f32 -> u32 [bf16(hi):bf16(lo)], round-half-up (hot path)
__device__ __forceinline__ u32 pack2(float hi, float lo) {
    union { float f; u32 u; } a, b; a.f = hi; b.f = lo;
    return __builtin_amdgcn_perm(a.u + 0x8000u, b.u + 0x8000u, 0x07060302u);
}
__device__ __forceinline__ short f2bf(float f) {   // RNE, one-time paths
    union { float f; u32 u; } v; v.f = f;
    return (short)((v.u + 0x7FFFu + ((v.u >> 16) & 1u)) >> 16);
}
// shifted softplus: softplus(x) - ln(2)
__device__ __forceinline__ float ssp(float x) {
    float t = __expf(-fabsf(x));
    float l = __logf(1.0f + t);
    return (fmaxf(x, 0.0f) - 0.69314718056f) + l;
}

__global__
__attribute__((amdgpu_flat_work_group_size(TPB, TPB), amdgpu_waves_per_eu(2, 2)))
void cfconv_kernel(const float* __restrict__ af,      // [B,N,D]
                   const float* __restrict__ dist,    // [B,E]
                   const int*   __restrict__ idx_j,   // [E]
                   const int*   __restrict__ seg_i,   // [E] (sorted)
                   const float* __restrict__ centers, // [NRBF]
                   const float* __restrict__ gam,     // [NRBF]
                   const float* __restrict__ W1,      // [NRBF,D]
                   const float* __restrict__ b1,      // [D]
                   const float* __restrict__ W2,      // [D,D]
                   const float* __restrict__ b2,      // [D]
                   float* __restrict__ out)           // [B,N,D]
{
    const int t    = threadIdx.x;
    const int lane = t & 63;
    const int w    = t >> 6;          // wave 0..3
    const int g    = lane >> 4;       // quad 0..3
    const int c0   = lane & 15;
    const int b    = blockIdx.y;
    const int e0   = blockIdx.x * EPB;

    // fragment-ready bf16 weights, PERMUTED columns:
    //   physical col c carries logical col 8*(c&15) + (c>>4)
    //   layout [cc][g][c][j], B[k][.], k = cc*32 + g*8 + j
    __shared__ __align__(16) short W1f[2 * 4 * D_ * 8];     // 16 KB
    __shared__ __align__(16) short W2f[4 * 4 * D_ * 8];     // 32 KB
    // per-wave h1, A-frag order: A2[w][c0w][m_swz][j] = h1[m][8*c0w+j]  (16 KB)
    __shared__ __align__(16) short A2[4][16][16][8];

    // ---- one-time: weights -> LDS frag layout (permuted logical columns)
    for (int i = t; i < NRBF * D_; i += TPB) {
        const int k = i >> 7, c = i & 127;
        W1f[(((k >> 5) * 4 + ((k >> 3) & 3)) * D_ + c) * 8 + (k & 7)] =
            f2bf(W1[(size_t)k * D_ + 8 * (c & 15) + (c >> 4)]);
    }
    for (int i = t; i < D_ * D_; i += TPB) {
        const int k = i >> 7, c = i & 127;
        W2f[(((k >> 5) * 4 + ((k >> 3) & 3)) * D_ + c) * 8 + (k & 7)] =
            f2bf(W2[(size_t)k * D_ + 8 * (c & 15) + (c >> 4)]);
    }
    __syncthreads();   // only block-wide barrier

    // biases in logical (permuted) order: col nt -> b[8*c0+nt]
    const vf8 b1r = *(const vf8*)&b1[8 * c0];
    const vf8 b2r = *(const vf8*)&b2[8 * c0];

    // rbf params for this lane's A-frag rows: k = cc*32 + g*8 + j
    vf8 gla, glb, cla, clb;
    #pragma unroll
    for (int j = 0; j < 8; ++j) {
        gla[j] = gam[g * 8 + j]      * 1.44269504f;   // pre-mul log2(e)
        glb[j] = gam[32 + g * 8 + j] * 1.44269504f;
        cla[j] = centers[g * 8 + j];
        clb[j] = centers[32 + g * 8 + j];
    }

    const float* dist_b = dist + (size_t)b * E_;
    const float* af_b   = af   + (size_t)b * N_ * D_;
    float*       out_b  = out  + (size_t)b * N_ * D_;

    const int eArow = e0 + w * WCH + (c0 >> 2) * GCH + (c0 & 3);  // A-row m=c0
    const int ebase = e0 + w * WCH + g * GCH;                     // epilogue quad

    int cur_seg = -1;
    vf8 pend = (vf8)0.0f;

    for (int s = 0; s < NTILES; ++s) {
        // ===== rbf A-fragments in registers =====
        const float dd = dist_b[eArow + s * 4];
        u32x4 qa, qb;
        #pragma unroll
        for (int p = 0; p < 4; ++p) {
            float x0 = dd - cla[2 * p];     float v0 = __builtin_amdgcn_exp2f(-gla[2 * p]     * x0 * x0);
            float x1 = dd - cla[2 * p + 1]; float v1 = __builtin_amdgcn_exp2f(-gla[2 * p + 1] * x1 * x1);
            qa[p] = pack2(v1, v0);
            float y0 = dd - clb[2 * p];     float u0 = __builtin_amdgcn_exp2f(-glb[2 * p]     * y0 * y0);
            float y1 = dd - clb[2 * p + 1]; float u1 = __builtin_amdgcn_exp2f(-glb[2 * p + 1] * y1 * y1);
            qb[p] = pack2(u1, u0);
        }
        const bf8 a0 = __builtin_bit_cast(bf8, qa);
        const bf8 a1 = __builtin_bit_cast(bf8, qb);

        // ===== GEMM1: h1 (cols permuted: phys nt*16+c0 -> logical 8*c0+nt) =====
        f32x4 hh[8];
        #pragma unroll
        for (int nt = 0; nt < 8; ++nt) {
            const bf8 w0 = *(const bf8*)&W1f[((0 * 4 + g) * D_ + nt * 16 + c0) * 8];
            const bf8 w1 = *(const bf8*)&W1f[((1 * 4 + g) * D_ + nt * 16 + c0) * 8];
            f32x4 acc = {0.f, 0.f, 0.f, 0.f};
            acc = __builtin_amdgcn_mfma_f32_16x16x32_bf16(a0, w0, acc, 0, 0, 0);
            acc = __builtin_amdgcn_mfma_f32_16x16x32_bf16(a1, w1, acc, 0, 0, 0);
            hh[nt] = acc;
        }

        // ===== ssp + pack + swizzled b128 store to per-wave A2 =====
        #pragma unroll
        for (int r = 0; r < 4; ++r) {
            u32x4 q;
            #pragma unroll
            for (int p = 0; p < 4; ++p) {
                float v0 = ssp(hh[2 * p][r]     + b1r[2 * p]);
                float v1 = ssp(hh[2 * p + 1][r] + b1r[2 * p + 1]);
                q[p] = pack2(v1, v0);
            }
            const int mphys = (g * 4 + r) ^ (c0 & 7);
            *(bf8*)&A2[w][c0][mphys][0] = __builtin_bit_cast(bf8, q);
        }
        // intra-wave dependency only (compiler inserts lgkmcnt)

        // ===== GEMM2 =====
        f32x4 facc[8];
        {
            bf8 pfr[4];
            #pragma unroll
            for (int cc = 0; cc < 4; ++cc) {
                const int c0w = cc * 4 + g;
                pfr[cc] = *(const bf8*)&A2[w][c0w][c0 ^ (c0w & 7)][0];
            }
            #pragma unroll
            for (int nt = 0; nt < 8; ++nt) {
                f32x4 acc = {0.f, 0.f, 0.f, 0.f};
                #pragma unroll
                for (int cc = 0; cc < 4; ++cc) {
                    const bf8 wf = *(const bf8*)&W2f[((cc * 4 + g) * D_ + nt * 16 + c0) * 8];
                    acc = __builtin_amdgcn_mfma_f32_16x16x32_bf16(pfr[cc], wf, acc, 0, 0, 0);
                }
                facc[nt] = acc;
            }
        }

        // ===== epilogue: contiguous gather, ssp, run-combine, atomics =====
        #pragma unroll
        for (int r = 0; r < 4; ++r) {
            const int e  = ebase + s * 4 + r;
            const int j  = idx_j[e];
            const int sg = seg_i[e];
            const vf8 nb = *(const vf8*)&af_b[(size_t)j * D_ + 8 * c0];  // 2x dwordx4
            vf8 msg;
            #pragma unroll
            for (int nt = 0; nt < 8; ++nt) {
                const float fv = ssp(facc[nt][r] + b2r[nt]);   // logical col 8*c0+nt
                msg[nt] = nb[nt] * fv;
            }
            if (sg != cur_seg) {
                if (cur_seg >= 0) {
                    float* o = out_b + (size_t)cur_seg * D_ + 8 * c0;
                    #pragma unroll
                    for (int nt = 0; nt < 8; ++nt) atomicAdd(o + nt, pend[nt]);
                }
                cur_seg = sg;
                pend = msg;
            } else {
                pend += msg;
            }
        }
    }
    if (cur_seg >= 0) {
        float* o = out_b + (size_t)cur_seg * D_ + 8 * c0;
        #pragma unroll
        for (int nt = 0; nt < 8; ++nt) atomicAdd(o + nt, pend[nt]);
    }
}

extern "C" void kernel_launch(void* const* d_in, const int* in_sizes, int n_in,
                              void* d_out, int out_size, void* d_ws, size_t ws_size,
                              hipStream_t stream) {
    const float* af      = (const float*)d_in[0];
    const float* dist    = (const float*)d_in[1];
    const int*   idx_j   = (const int*)d_in[2];
    const int*   seg_i   = (const int*)d_in[3];
    const float* centers = (const float*)d_in[4];
    const float* gam     = (const float*)d_in[5];
    const float* W1      = (const float*)d_in[6];
    const float* b1      = (const float*)d_in[7];
    const float* W2      = (const float*)d_in[8];
    const float* b2      = (const float*)d_in[9];
    float* out = (float*)d_out;

    hipMemsetAsync(out, 0, (size_t)out_size * sizeof(float), stream);

    dim3 grid(NBLK, B_);
    cfconv_kernel<<<grid, TPB, 0, stream>>>(af, dist, idx_j, seg_i,
                                            centers, gam, W1, b1, W2, b2, out);
}

// Round 8
// 358.081 us; speedup vs baseline: 1.3496x; 1.3108x over previous
//
#include <hip/hip_runtime.h>
#include <math.h>

#define B_ 2
#define N_ 25000
#define E_ 400000
#define D_ 128
#define NRBF 64

#define TPB 256               // 4 waves
#define NTILES 25             // tiles per wave; 16 edges per wave-tile
#define WCH 400               // edges per wave
#define GCH 100               // edges per (wave, lane-quad) contiguous chunk
#define EPB (4 * WCH)         // 1600 edges per block
#define NBLK (E_ / EPB)       // 250 blocks per batch

typedef short bf8    __attribute__((ext_vector_type(8)));   // MFMA A/B frag
typedef float f32x4  __attribute__((ext_vector_type(4)));   // MFMA C/D frag
typedef float vf8    __attribute__((ext_vector_type(8)));
typedef unsigned int u32;
typedef u32 u32x4    __attribute__((ext_vector_type(4)));

// pack two f32 -> u32 [bf16(hi):bf16(lo)], round-half-up (hot path)
__device__ __forceinline__ u32 pack2(float hi, float lo) {
    union { float f; u32 u; } a, b; a.f = hi; b.f = lo;
    return __builtin_amdgcn_perm(a.u + 0x8000u, b.u + 0x8000u, 0x07060302u);
}
__device__ __forceinline__ short f2bf(float f) {   // RNE, one-time paths
    union { float f; u32 u; } v; v.f = f;
    return (short)((v.u + 0x7FFFu + ((v.u >> 16) & 1u)) >> 16);
}
// shifted softplus: softplus(x) - ln(2)
__device__ __forceinline__ float ssp(float x) {
    float t = __expf(-fabsf(x));
    float l = __logf(1.0f + t);
    return (fmaxf(x, 0.0f) - 0.69314718056f) + l;
}

__global__ __launch_bounds__(TPB, 2)
void cfconv_kernel(const float* __restrict__ af,      // [B,N,D]
                   const float* __restrict__ dist,    // [B,E]
                   const int*   __restrict__ idx_j,   // [E]
                   const int*   __restrict__ seg_i,   // [E] (sorted)
                   const float* __restrict__ centers, // [NRBF]
                   const float* __restrict__ gam,     // [NRBF]
                   const float* __restrict__ W1,      // [NRBF,D]
                   const float* __restrict__ b1,      // [D]
                   const float* __restrict__ W2,      // [D,D]
                   const float* __restrict__ b2,      // [D]
                   float* __restrict__ out)           // [B,N,D]
{
    const int t    = threadIdx.x;
    const int lane = t & 63;
    const int w    = t >> 6;          // wave 0..3
    const int g    = lane >> 4;       // quad 0..3
    const int c0   = lane & 15;
    const int b    = blockIdx.y;
    const int e0   = blockIdx.x * EPB;

    // fragment-ready bf16 weights, PERMUTED columns:
    //   physical col c carries logical col 8*(c&15) + (c>>4)
    //   layout [cc][g][c][j], B[k][.], k = cc*32 + g*8 + j
    __shared__ __align__(16) short W1f[2 * 4 * D_ * 8];     // 16 KB
    __shared__ __align__(16) short W2f[4 * 4 * D_ * 8];     // 32 KB
    // per-wave h1, A-frag order: A2[w][kb][m ^ (kb&7)][j] = h1[m][8*kb+j]  (16 KB)
    __shared__ __align__(16) short A2[4][16][16][8];
    // small params in LDS so they are per-tile transients, not persistent VGPRs
    __shared__ __align__(16) float prm[2][NRBF];            // [0]=gam*log2e, [1]=centers
    __shared__ __align__(16) float bia[2][D_];              // b1, b2 (natural order)

    // ---- one-time staging
    for (int i = t; i < NRBF * D_; i += TPB) {
        const int k = i >> 7, c = i & 127;
        W1f[(((k >> 5) * 4 + ((k >> 3) & 3)) * D_ + c) * 8 + (k & 7)] =
            f2bf(W1[(size_t)k * D_ + 8 * (c & 15) + (c >> 4)]);
    }
    for (int i = t; i < D_ * D_; i += TPB) {
        const int k = i >> 7, c = i & 127;
        W2f[(((k >> 5) * 4 + ((k >> 3) & 3)) * D_ + c) * 8 + (k & 7)] =
            f2bf(W2[(size_t)k * D_ + 8 * (c & 15) + (c >> 4)]);
    }
    if (t < NRBF) { prm[0][t] = gam[t] * 1.44269504f; prm[1][t] = centers[t]; }
    if (t >= 128 && t < 256) { bia[0][t - 128] = b1[t - 128]; bia[1][t - 128] = b2[t - 128]; }
    __syncthreads();   // only block-wide barrier

    const float* dist_b = dist + (size_t)b * E_;
    const float* af_b   = af   + (size_t)b * N_ * D_;
    float*       out_b  = out  + (size_t)b * N_ * D_;

    const int eArow = e0 + w * WCH + (c0 >> 2) * GCH + (c0 & 3);  // A-row m=c0
    const int ebase = e0 + w * WCH + g * GCH;                     // epilogue quad

    int cur_seg = -1;
    vf8 pend = (vf8)0.0f;

    for (int s = 0; s < NTILES; ++s) {
        // ===== P0: rbf A-fragments (params read from LDS, transient) =====
        bf8 a0, a1;
        {
            const float dd = dist_b[eArow + s * 4];
            const vf8 gla = *(const vf8*)&prm[0][g * 8];
            const vf8 glb = *(const vf8*)&prm[0][32 + g * 8];
            const vf8 cla = *(const vf8*)&prm[1][g * 8];
            const vf8 clb = *(const vf8*)&prm[1][32 + g * 8];
            u32x4 qa, qb;
            #pragma unroll
            for (int p = 0; p < 4; ++p) {
                float x0 = dd - cla[2 * p];     float v0 = __builtin_amdgcn_exp2f(-gla[2 * p]     * x0 * x0);
                float x1 = dd - cla[2 * p + 1]; float v1 = __builtin_amdgcn_exp2f(-gla[2 * p + 1] * x1 * x1);
                qa[p] = pack2(v1, v0);
                float y0 = dd - clb[2 * p];     float u0 = __builtin_amdgcn_exp2f(-glb[2 * p]     * y0 * y0);
                float y1 = dd - clb[2 * p + 1]; float u1 = __builtin_amdgcn_exp2f(-glb[2 * p + 1] * y1 * y1);
                qb[p] = pack2(u1, u0);
            }
            a0 = __builtin_bit_cast(bf8, qa);
            a1 = __builtin_bit_cast(bf8, qb);
        }
        __builtin_amdgcn_sched_barrier(0);

        // ===== P1: GEMM1 (cols permuted: phys nt*16+c0 -> logical 8*c0+nt) =====
        f32x4 hh[8];
        #pragma unroll
        for (int nt = 0; nt < 8; ++nt) {
            const bf8 w0 = *(const bf8*)&W1f[((0 * 4 + g) * D_ + nt * 16 + c0) * 8];
            const bf8 w1 = *(const bf8*)&W1f[((1 * 4 + g) * D_ + nt * 16 + c0) * 8];
            f32x4 acc = {0.f, 0.f, 0.f, 0.f};
            acc = __builtin_amdgcn_mfma_f32_16x16x32_bf16(a0, w0, acc, 0, 0, 0);
            acc = __builtin_amdgcn_mfma_f32_16x16x32_bf16(a1, w1, acc, 0, 0, 0);
            hh[nt] = acc;
        }

        // ===== P2: ssp + pack + swizzled b128 store to per-wave A2 =====
        {
            const vf8 b1r = *(const vf8*)&bia[0][8 * c0];
            #pragma unroll
            for (int r = 0; r < 4; ++r) {
                u32x4 q;
                #pragma unroll
                for (int p = 0; p < 4; ++p) {
                    float v0 = ssp(hh[2 * p][r]     + b1r[2 * p]);
                    float v1 = ssp(hh[2 * p + 1][r] + b1r[2 * p + 1]);
                    q[p] = pack2(v1, v0);
                }
                const int mphys = (g * 4 + r) ^ (c0 & 7);
                *(bf8*)&A2[w][c0][mphys][0] = __builtin_bit_cast(bf8, q);
            }
        }
        __builtin_amdgcn_sched_barrier(0);

        // ===== P3: GEMM2 =====
        f32x4 facc[8];
        {
            bf8 pfr[4];
            #pragma unroll
            for (int cc = 0; cc < 4; ++cc) {
                const int kb = cc * 4 + g;
                pfr[cc] = *(const bf8*)&A2[w][kb][c0 ^ (kb & 7)][0];
            }
            #pragma unroll
            for (int nt = 0; nt < 8; ++nt) {
                f32x4 acc = {0.f, 0.f, 0.f, 0.f};
                #pragma unroll
                for (int cc = 0; cc < 4; ++cc) {
                    const bf8 wf = *(const bf8*)&W2f[((cc * 4 + g) * D_ + nt * 16 + c0) * 8];
                    acc = __builtin_amdgcn_mfma_f32_16x16x32_bf16(pfr[cc], wf, acc, 0, 0, 0);
                }
                facc[nt] = acc;
            }
        }
        __builtin_amdgcn_sched_barrier(0);

        // ===== P4: epilogue — gather, ssp, sorted-run combine, atomics =====
        {
            const int e4 = ebase + s * 4;
            const int4 jv = *(const int4*)&idx_j[e4];
            const int4 sv = *(const int4*)&seg_i[e4];
            const vf8 b2r = *(const vf8*)&bia[1][8 * c0];
            #define EDGE_STEP(R, JJ, SG)                                        \
            {                                                                   \
                const vf8 nb = *(const vf8*)&af_b[(size_t)(JJ) * D_ + 8 * c0];  \
                vf8 msg;                                                        \
                _Pragma("unroll")                                               \
                for (int nt = 0; nt < 8; ++nt) {                                \
                    const float fv = ssp(facc[nt][R] + b2r[nt]);                \
                    msg[nt] = nb[nt] * fv;                                      \
                }                                                               \
                if ((SG) != cur_seg) {                                          \
                    if (cur_seg >= 0) {                                         \
                        float* o = out_b + (size_t)cur_seg * D_ + 8 * c0;       \
                        _Pragma("unroll")                                       \
                        for (int nt = 0; nt < 8; ++nt) atomicAdd(o + nt, pend[nt]); \
                    }                                                           \
                    cur_seg = (SG);                                             \
                    pend = msg;                                                 \
                } else {                                                        \
                    pend += msg;                                                \
                }                                                               \
            }
            EDGE_STEP(0, jv.x, sv.x)
            EDGE_STEP(1, jv.y, sv.y)
            EDGE_STEP(2, jv.z, sv.z)
            EDGE_STEP(3, jv.w, sv.w)
            #undef EDGE_STEP
        }
    }
    if (cur_seg >= 0) {
        float* o = out_b + (size_t)cur_seg * D_ + 8 * c0;
        #pragma unroll
        for (int nt = 0; nt < 8; ++nt) atomicAdd(o + nt, pend[nt]);
    }
}

extern "C" void kernel_launch(void* const* d_in, const int* in_sizes, int n_in,
                              void* d_out, int out_size, void* d_ws, size_t ws_size,
                              hipStream_t stream) {
    const float* af      = (const float*)d_in[0];
    const float* dist    = (const float*)d_in[1];
    const int*   idx_j   = (const int*)d_in[2];
    const int*   seg_i   = (const int*)d_in[3];
    const float* centers = (const float*)d_in[4];
    const float* gam     = (const float*)d_in[5];
    const float* W1      = (const float*)d_in[6];
    const float* b1      = (const float*)d_in[7];
    const float* W2      = (const float*)d_in[8];
    const float* b2      = (const float*)d_in[9];
    float* out = (float*)d_out;

    hipMemsetAsync(out, 0, (size_t)out_size * sizeof(float), stream);

    dim3 grid(NBLK, B_);
    cfconv_kernel<<<grid, TPB, 0, stream>>>(af, dist, idx_j, seg_i,
                                            centers, gam, W1, b1, W2, b2, out);
}